// Round 8
// baseline (360.189 us; speedup 1.0000x reference)
//
#include <hip/hip_runtime.h>
#include <hip/hip_bf16.h>
#include <math.h>

// B=1, S=2048, D=2048, H=32, KV=8, HD=64, G=4.
#define S_LEN 2048
#define D_MODEL 2048
#define N_H 32
#define N_KV 8
#define HD 64

typedef __attribute__((ext_vector_type(8))) short short8;   // 8 bf16 (A/B frag)
typedef __attribute__((ext_vector_type(4))) float floatx4;  // C/D frag
typedef unsigned short u16;
typedef unsigned int u32;

#define QSCALE 0.18033688011112042f   // (1/8) * log2(e): folded into Q -> exp2 domain

#if defined(__has_builtin)
#if __has_builtin(__builtin_amdgcn_exp2f)
#define EXP2(x) __builtin_amdgcn_exp2f(x)
#else
#define EXP2(x) __expf(0.6931471805599453f * (x))
#endif
#else
#define EXP2(x) __expf(0.6931471805599453f * (x))
#endif

// round-to-nearest-even fp32 -> bf16
__device__ __forceinline__ u16 f2bf(float f) {
    union { float f; u32 u; } v; v.f = f;
    u32 r = v.u + 0x7fffu + ((v.u >> 16) & 1u);
    return (u16)(r >> 16);
}
// cheap round-half-up fp32 -> bf16 (2 ops) for P (values >= 0)
__device__ __forceinline__ u16 f2bf_fast(float f) {
    union { float f; u32 u; } v; v.f = f;
    return (u16)((v.u + 0x8000u) >> 16);
}

// async global->LDS, 16B/lane. LDS dest = wave-uniform base + lane*16.
__device__ __forceinline__ void gload16(const void* gp, void* lp) {
    __builtin_amdgcn_global_load_lds(
        (const __attribute__((address_space(1))) unsigned int*)gp,
        (__attribute__((address_space(3))) unsigned int*)lp,
        16, 0, 0);
}

// ---------------------------------------------------------------------------
// One-pass cast of all fp32 inputs to bf16:
//   x (2048 rows) -> xb, Wq|Wk|Wv (2048+512+512) -> wqkv, Wo (2048) -> wob
// ---------------------------------------------------------------------------
__global__ __launch_bounds__(256) void cast_all(const float* __restrict__ x,
                                                const float* __restrict__ Wq,
                                                const float* __restrict__ Wk,
                                                const float* __restrict__ Wv,
                                                const float* __restrict__ Wo,
                                                u16* __restrict__ xb,
                                                u16* __restrict__ wqkv,
                                                u16* __restrict__ wob) {
    const int i = (blockIdx.x * 256 + threadIdx.x) * 4;   // < 7168*2048
    const int row = i >> 11;
    const int col = i & 2047;
    const float* src;
    u16* dst;
    if (row < 2048)      { src = x  + (size_t)row * 2048 + col;          dst = xb + i; }
    else if (row < 4096) { src = Wq + (size_t)(row - 2048) * 2048 + col; dst = wqkv + (i - 2048 * 2048); }
    else if (row < 4608) { src = Wk + (size_t)(row - 4096) * 2048 + col; dst = wqkv + (i - 2048 * 2048); }
    else if (row < 5120) { src = Wv + (size_t)(row - 4608) * 2048 + col; dst = wqkv + (i - 2048 * 2048); }
    else                 { src = Wo + (size_t)(row - 5120) * 2048 + col; dst = wob + (i - 5120 * 2048); }
    const float4 v = *(const float4*)src;
    ushort4 o;
    o.x = f2bf(v.x); o.y = f2bf(v.y); o.z = f2bf(v.z); o.w = f2bf(v.w);
    *(ushort4*)dst = o;
}

// ---------------------------------------------------------------------------
// Barrier-free register-direct QKV GEMM (no LDS):
// C[M,N] = A[M,K] @ B[N,K]^T; each wave loads its MFMA fragments straight
// from global (row-major, same layout as the LDS path) into VGPRs,
// double-buffered in registers. No __syncthreads -> no vmcnt(0) drains;
// latency hidden by 3 waves/SIMD + compiler vmcnt(N) pipelining; sharing
// within a block (2 waves share A rows, 2 share B cols) is served by L1/L2.
// Wave tile 32x64 (2x4 acc), block 64x128, grid 32x24 = 768 blocks = 3/CU.
// Fused RoPE/pack/scale epilogue (wave covers exactly one 64-wide head).
// ---------------------------------------------------------------------------
__global__ __launch_bounds__(256, 3) void gemm_qkv(const u16* __restrict__ A,
                                                   const u16* __restrict__ B,
                                                   u16* __restrict__ Qh,
                                                   u16* __restrict__ Kh,
                                                   u16* __restrict__ Vt,
                                                   const float* __restrict__ inv_freq,
                                                   int K) {
    const int tid  = threadIdx.x;
    const int w    = tid >> 6;
    const int lane = tid & 63;
    const int lr   = lane & 15;
    const int quad = lane >> 4;
    const int bm = blockIdx.x * 64, bn = blockIdx.y * 128;
    const int wm = (w & 1) * 32;          // 2 m-strips of 32
    const int wn = (w >> 1) * 64;         // 2 n-strips of 64 (= one head)

    const u16* Ap[2];
    const u16* Bp[4];
#pragma unroll
    for (int s = 0; s < 2; ++s)
        Ap[s] = A + (size_t)(bm + wm + s * 16 + lr) * K + quad * 8;
#pragma unroll
    for (int t = 0; t < 4; ++t)
        Bp[t] = B + (size_t)(bn + wn + t * 16 + lr) * K + quad * 8;

    floatx4 acc[2][4];
#pragma unroll
    for (int i = 0; i < 2; ++i)
#pragma unroll
        for (int j = 0; j < 4; ++j) acc[i][j] = floatx4{0.f, 0.f, 0.f, 0.f};

    short8 a0[2], a1[2], b0[4], b1[4];
#pragma unroll
    for (int s = 0; s < 2; ++s) a0[s] = *(const short8*)(Ap[s]);
#pragma unroll
    for (int t = 0; t < 4; ++t) b0[t] = *(const short8*)(Bp[t]);

    for (int k0 = 0; k0 < K; k0 += 64) {
        // prefetch k0+32 while computing k0
#pragma unroll
        for (int s = 0; s < 2; ++s) a1[s] = *(const short8*)(Ap[s] + k0 + 32);
#pragma unroll
        for (int t = 0; t < 4; ++t) b1[t] = *(const short8*)(Bp[t] + k0 + 32);
#pragma unroll
        for (int im = 0; im < 2; ++im)
#pragma unroll
            for (int in = 0; in < 4; ++in)
                acc[im][in] = __builtin_amdgcn_mfma_f32_16x16x32_bf16(
                    a0[im], b0[in], acc[im][in], 0, 0, 0);
        if (k0 + 64 < K) {                 // prefetch k0+64 while computing k0+32
#pragma unroll
            for (int s = 0; s < 2; ++s) a0[s] = *(const short8*)(Ap[s] + k0 + 64);
#pragma unroll
            for (int t = 0; t < 4; ++t) b0[t] = *(const short8*)(Bp[t] + k0 + 64);
        }
#pragma unroll
        for (int im = 0; im < 2; ++im)
#pragma unroll
            for (int in = 0; in < 4; ++in)
                acc[im][in] = __builtin_amdgcn_mfma_f32_16x16x32_bf16(
                    a1[im], b1[in], acc[im][in], 0, 0, 0);
    }

    // C/D layout: col = lane&15 (+in*16), row = quad*4 + reg.
    // Wave covers cols c0..c0+63 = exactly one head.
    const int c0 = bn + wn;
    if (bn < 2048) {                           // ---- Q: rope + scale ----
        const int h = c0 >> 6;
#pragma unroll
        for (int p = 0; p < 2; ++p) {
            const int d = p * 16 + lr;         // 0..31
            const float fr = inv_freq[d];
#pragma unroll
            for (int im = 0; im < 2; ++im)
#pragma unroll
                for (int r = 0; r < 4; ++r) {
                    const int s = bm + wm + im * 16 + quad * 4 + r;
                    float sn, cs;
                    sincosf((float)s * fr, &sn, &cs);
                    const float xl = acc[im][p][r], xh = acc[im][p + 2][r];
                    u16* qrow = Qh + ((size_t)h * S_LEN + s) * HD;
                    qrow[d]      = f2bf((xl * cs - xh * sn) * QSCALE);
                    qrow[d + 32] = f2bf((xh * cs + xl * sn) * QSCALE);
                }
        }
    } else if (bn < 2560) {                    // ---- K: rope ----
        const int kv = (c0 - 2048) >> 6;
#pragma unroll
        for (int p = 0; p < 2; ++p) {
            const int d = p * 16 + lr;
            const float fr = inv_freq[d];
#pragma unroll
            for (int im = 0; im < 2; ++im)
#pragma unroll
                for (int r = 0; r < 4; ++r) {
                    const int s = bm + wm + im * 16 + quad * 4 + r;
                    float sn, cs;
                    sincosf((float)s * fr, &sn, &cs);
                    const float xl = acc[im][p][r], xh = acc[im][p + 2][r];
                    u16* krow = Kh + ((size_t)kv * S_LEN + s) * HD;
                    krow[d]      = f2bf(xl * cs - xh * sn);
                    krow[d + 32] = f2bf(xh * cs + xl * sn);
                }
        }
    } else {                                   // ---- V: transpose pack ----
        const int kv = (c0 - 2560) >> 6;
#pragma unroll
        for (int im = 0; im < 2; ++im)
#pragma unroll
            for (int in = 0; in < 4; ++in) {
                const int dfull = in * 16 + lr;
                const int s0 = bm + wm + im * 16 + quad * 4;
                ushort4 o;
                o.x = f2bf(acc[im][in][0]); o.y = f2bf(acc[im][in][1]);
                o.z = f2bf(acc[im][in][2]); o.w = f2bf(acc[im][in][3]);
                *(ushort4*)&Vt[((size_t)kv * HD + dfull) * S_LEN + s0] = o;
            }
    }
}

// ---------------------------------------------------------------------------
// Barrier-free register-direct output projection (same structure, fp32 C).
// Wave tile 32x64, block 64x128, grid 32x16 = 512 blocks = 2/CU.
// ---------------------------------------------------------------------------
__global__ __launch_bounds__(256, 2) void gemm_out(const u16* __restrict__ A,
                                                   const u16* __restrict__ B,
                                                   float* __restrict__ Cf,
                                                   int N, int K) {
    const int tid  = threadIdx.x;
    const int w    = tid >> 6;
    const int lane = tid & 63;
    const int lr   = lane & 15;
    const int quad = lane >> 4;
    const int bm = blockIdx.x * 64, bn = blockIdx.y * 128;
    const int wm = (w & 1) * 32;
    const int wn = (w >> 1) * 64;

    const u16* Ap[2];
    const u16* Bp[4];
#pragma unroll
    for (int s = 0; s < 2; ++s)
        Ap[s] = A + (size_t)(bm + wm + s * 16 + lr) * K + quad * 8;
#pragma unroll
    for (int t = 0; t < 4; ++t)
        Bp[t] = B + (size_t)(bn + wn + t * 16 + lr) * K + quad * 8;

    floatx4 acc[2][4];
#pragma unroll
    for (int i = 0; i < 2; ++i)
#pragma unroll
        for (int j = 0; j < 4; ++j) acc[i][j] = floatx4{0.f, 0.f, 0.f, 0.f};

    short8 a0[2], a1[2], b0[4], b1[4];
#pragma unroll
    for (int s = 0; s < 2; ++s) a0[s] = *(const short8*)(Ap[s]);
#pragma unroll
    for (int t = 0; t < 4; ++t) b0[t] = *(const short8*)(Bp[t]);

    for (int k0 = 0; k0 < K; k0 += 64) {
#pragma unroll
        for (int s = 0; s < 2; ++s) a1[s] = *(const short8*)(Ap[s] + k0 + 32);
#pragma unroll
        for (int t = 0; t < 4; ++t) b1[t] = *(const short8*)(Bp[t] + k0 + 32);
#pragma unroll
        for (int im = 0; im < 2; ++im)
#pragma unroll
            for (int in = 0; in < 4; ++in)
                acc[im][in] = __builtin_amdgcn_mfma_f32_16x16x32_bf16(
                    a0[im], b0[in], acc[im][in], 0, 0, 0);
        if (k0 + 64 < K) {
#pragma unroll
            for (int s = 0; s < 2; ++s) a0[s] = *(const short8*)(Ap[s] + k0 + 64);
#pragma unroll
            for (int t = 0; t < 4; ++t) b0[t] = *(const short8*)(Bp[t] + k0 + 64);
        }
#pragma unroll
        for (int im = 0; im < 2; ++im)
#pragma unroll
            for (int in = 0; in < 4; ++in)
                acc[im][in] = __builtin_amdgcn_mfma_f32_16x16x32_bf16(
                    a1[im], b1[in], acc[im][in], 0, 0, 0);
    }

#pragma unroll
    for (int im = 0; im < 2; ++im)
#pragma unroll
        for (int in = 0; in < 4; ++in) {
            const int row0 = bm + wm + im * 16 + quad * 4;
            const int col  = bn + wn + in * 16 + lr;
#pragma unroll
            for (int r = 0; r < 4; ++r)
                Cf[(size_t)(row0 + r) * N + col] = acc[im][in][r];
        }
}

// ---------------------------------------------------------------------------
// MFMA flash attention (causal, GQA), exp2 domain, MAX-FREE softmax.
// Unchanged from the round-7 PASSING kernel (XOR swizzle conflict-free,
// double-buffered K/V, 1024 blocks heavy-first).
// ---------------------------------------------------------------------------
__global__ __launch_bounds__(256) void attn_mfma(const u16* __restrict__ Qh,
                                                 const u16* __restrict__ Kh,
                                                 const u16* __restrict__ Vt,
                                                 u16* __restrict__ AO) {
    __shared__ u16 QPs[64 * 64];         // Q tile, then P (wave-private rows)
    __shared__ u16 Ks[2][64 * 64];
    __shared__ u16 Vs[2][64 * 64];       // V^T tile: [d][s_local]

    const int bid = blockIdx.x;
    const int h   = bid & 31;
    const int qb  = 31 - (bid >> 5);     // heavy q-tiles first (qb 0..31)
    const int kv  = h >> 2;
    const int tid  = threadIdx.x;
    const int w    = tid >> 6;
    const int lr   = tid & 15;
    const int quad = (tid >> 4) & 3;
    const int grow = tid >> 3;           // staging row 0..31
    const int gp   = tid & 7;            // staging chunk position 0..7

    const u16* Qg = Qh + ((size_t)h * S_LEN + (size_t)qb * 64) * HD;
    const u16* Kg = Kh + (size_t)kv * S_LEN * HD;
    const u16* Vg = Vt + (size_t)kv * HD * S_LEN;

    // ---- stage Q + K/V tile 0 (swizzled global chunk per lane) ----
#pragma unroll
    for (int j = 0; j < 2; ++j) {
        const int r = j * 32 + grow;
        gload16(Qg + (size_t)r * HD + ((gp ^ (r & 7)) * 8), QPs + r * 64 + gp * 8);
        gload16(Kg + (size_t)r * HD + ((gp ^ (r & 7)) * 8), &Ks[0][r * 64 + gp * 8]);
        gload16(Vg + (size_t)r * S_LEN + ((gp ^ (r & 7)) * 8), &Vs[0][r * 64 + gp * 8]);
    }
    __syncthreads();

    const int wq0 = qb * 64 + w * 16;    // wave's first global q row

    // Q A-frags (wave-private rows w*16..w*16+15; swizzled read)
    short8 qf[2];
#pragma unroll
    for (int kh = 0; kh < 2; ++kh) {
        const int row = w * 16 + lr;
        const int c   = kh * 4 + quad;
        qf[kh] = *(const short8*)&QPs[row * 64 + ((c ^ (row & 7)) * 8)];
    }
    // no barrier needed: P writes below touch only this wave's own 16 rows

    float l_st[4] = {0.f, 0.f, 0.f, 0.f};
    floatx4 oacc[4];
#pragma unroll
    for (int dn = 0; dn < 4; ++dn) oacc[dn] = floatx4{0.f, 0.f, 0.f, 0.f};

    for (int kt = 0; kt <= qb; ++kt) {
        const int buf = kt & 1;
        if (kt < qb) {                   // prefetch next K/V tile
            const int nb = buf ^ 1;
#pragma unroll
            for (int j = 0; j < 2; ++j) {
                const int r = j * 32 + grow;
                gload16(Kg + (size_t)((kt + 1) * 64 + r) * HD + ((gp ^ (r & 7)) * 8),
                        &Ks[nb][r * 64 + gp * 8]);
                gload16(Vg + (size_t)r * S_LEN + (kt + 1) * 64 + ((gp ^ (r & 7)) * 8),
                        &Vs[nb][r * 64 + gp * 8]);
            }
        }
        if (64 * kt <= wq0 + 15) {       // wave has unmasked work this tile
            // ---- S = Q K^T ----
            floatx4 st[4];
#pragma unroll
            for (int in = 0; in < 4; ++in) st[in] = floatx4{0.f, 0.f, 0.f, 0.f};
#pragma unroll
            for (int in = 0; in < 4; ++in)
#pragma unroll
                for (int kh = 0; kh < 2; ++kh) {
                    const int row = in * 16 + lr;
                    const int c   = kh * 4 + quad;
                    const short8 kf = *(const short8*)
                        &Ks[buf][row * 64 + ((c ^ (row & 7)) * 8)];
                    st[in] = __builtin_amdgcn_mfma_f32_16x16x32_bf16(
                        qf[kh], kf, st[in], 0, 0, 0);
                }

            // ---- causal mask + max-free exp2 + l accumulation ----
            const bool need_mask = (kt * 64 + 63) > wq0;
#pragma unroll
            for (int r = 0; r < 4; ++r) {
                float ps = 0.f;
#pragma unroll
                for (int in = 0; in < 4; ++in) {
                    float s = st[in][r];
                    if (need_mask) {
                        const int rg = wq0 + quad * 4 + r;
                        const int cg = kt * 64 + in * 16 + lr;
                        if (cg > rg) s = -1e30f;
                    }
                    const float p = EXP2(s);
                    st[in][r] = p;
                    ps += p;
                }
                l_st[r] += ps;
            }

            // ---- P -> LDS (wave-private rows, swizzled positions) ----
#pragma unroll
            for (int in = 0; in < 4; ++in)
#pragma unroll
                for (int r = 0; r < 4; ++r) {
                    const int prow = w * 16 + quad * 4 + r;
                    const int col  = in * 16 + lr;
                    QPs[prow * 64 + (((col >> 3) ^ (prow & 7)) * 8) + (col & 7)] =
                        f2bf_fast(st[in][r]);
                }

            // ---- O += P V ----
#pragma unroll
            for (int kc = 0; kc < 2; ++kc) {
                const int prow = w * 16 + lr;
                const short8 pf = *(const short8*)
                    &QPs[prow * 64 + (((kc * 4 + quad) ^ (prow & 7)) * 8)];
#pragma unroll
                for (int dn = 0; dn < 4; ++dn) {
                    const int vrow = dn * 16 + lr;
                    const int c    = kc * 4 + quad;
                    const short8 vf = *(const short8*)
                        &Vs[buf][vrow * 64 + ((c ^ (vrow & 7)) * 8)];
                    oacc[dn] = __builtin_amdgcn_mfma_f32_16x16x32_bf16(
                        pf, vf, oacc[dn], 0, 0, 0);
                }
            }
        }
        __syncthreads();   // publishes prefetched tile; guards buffer reuse
    }

    // epilogue: reduce l across the 16 col-lanes, normalize, write bf16
#pragma unroll
    for (int r = 0; r < 4; ++r) {
        float lv = l_st[r];
#pragma unroll
        for (int mk = 1; mk < 16; mk <<= 1)
            lv += __shfl_xor(lv, mk);
        const float inv = 1.f / lv;
        const size_t row = (size_t)(wq0 + quad * 4 + r);
#pragma unroll
        for (int dn = 0; dn < 4; ++dn)
            AO[row * D_MODEL + h * 64 + dn * 16 + lr] =
                f2bf(oacc[dn][r] * inv);
    }
}

// ---------------------------------------------------------------------------
extern "C" void kernel_launch(void* const* d_in, const int* in_sizes, int n_in,
                              void* d_out, int out_size, void* d_ws, size_t ws_size,
                              hipStream_t stream) {
    const float* x        = (const float*)d_in[0];  // [2048, 2048]
    const float* Wq       = (const float*)d_in[1];  // [2048, 2048]
    const float* Wk       = (const float*)d_in[2];  // [512, 2048]
    const float* Wv       = (const float*)d_in[3];  // [512, 2048]
    const float* Wo       = (const float*)d_in[4];  // [2048, 2048]
    const float* inv_freq = (const float*)d_in[5];  // [32]
    float* out = (float*)d_out;                     // [2048, 2048] fp32

    const size_t ME = 1 << 20;
    u16* xb   = (u16*)d_ws;          // 4M  x bf16
    u16* wqkv = xb   + 4 * ME;       // 6M  [3072][2048]
    u16* wob  = wqkv + 6 * ME;       // 4M
    u16* qhb  = wob  + 4 * ME;       // 4M  Q[h][s][d]  (pre-scaled, exp2 domain)
    u16* khb  = qhb  + 4 * ME;       // 1M  K[kv][s][d]
    u16* vtb  = khb  + 1 * ME;       // 1M  Vt[kv][d][s]
    u16* aob  = vtb  + 1 * ME;       // 4M  ao[s][h*64+d]

    const dim3 b256(256);

    // single-pass bf16 casts (x + all weights)
    cast_all<<<14336, b256, 0, stream>>>(x, Wq, Wk, Wv, Wo, xb, wqkv, wob);

    // fused QKV projection + RoPE + pack (+ Q softmax/log2e scale)
    gemm_qkv<<<dim3(32, 24), b256, 0, stream>>>(
        xb, wqkv, qhb, khb, vtb, inv_freq, D_MODEL);

    // causal GQA flash attention (1024 blocks, 64 q-rows each)
    attn_mfma<<<dim3(1024), b256, 0, stream>>>(qhb, khb, vtb, aob);

    // output projection (barrier-free register-direct)
    gemm_out<<<dim3(32, 16), b256, 0, stream>>>(
        aob, wob, out, D_MODEL, D_MODEL);
}